// Round 1
// baseline (1422.899 us; speedup 1.0000x reference)
//
#include <hip/hip_runtime.h>

// Heat equation, 2 materials. N=512, 499 steps, every frame written to d_out.
// Baseline: one kernel dispatch per step; frame t reads frame t-1 in-place
// from d_out (frame -1 = u0). All f32.

#define GN 512
#define NSTEPS 499      // NUM_STEPS - 1 scan iterations
#define MBND 256        // columns [0, MBND) are material 1

// dx = 1/511; 1/dx^2 = 511*511 = 261121
#define INV_DX2 261121.0f
#define DT 5e-7f

__global__ __launch_bounds__(256) void heat_step(
    const float* __restrict__ Tin, float* __restrict__ Tout,
    const float* __restrict__ k1p, const float* __restrict__ k2p,
    const float* __restrict__ a1p, const float* __restrict__ a2p)
{
    const int idx = blockIdx.x * blockDim.x + threadIdx.x;   // 0 .. 512*512-1
    const int i = idx >> 9;
    const int j = idx & (GN - 1);

    float out;
    if (i == 0 || i == GN - 1 || j == 0 || j == GN - 1) {
        // Dirichlet zero boundaries (applied last in reference -> wins over
        // the interface column at rows 0 and N-1)
        out = 0.0f;
    } else if (j == MBND - 1) {
        // interface continuity from OLD T neighbors
        const float k1 = k1p[0];
        const float k2 = k2p[0];
        out = (k1 * Tin[idx + 1] + k2 * Tin[idx - 1]) / (k1 + k2);
    } else {
        const float alpha = (j < MBND) ? a1p[0] : a2p[0];
        const float c  = Tin[idx];
        const float up = Tin[idx - GN];
        const float dn = Tin[idx + GN];
        const float lf = Tin[idx - 1];
        const float rt = Tin[idx + 1];
        const float lap = (up + dn + lf + rt - 4.0f * c) * INV_DX2;
        out = __fmaf_rn(DT * alpha, lap, c);
    }
    Tout[idx] = out;
}

extern "C" void kernel_launch(void* const* d_in, const int* in_sizes, int n_in,
                              void* d_out, int out_size, void* d_ws, size_t ws_size,
                              hipStream_t stream)
{
    const float* u0 = (const float*)d_in[0];
    const float* k1 = (const float*)d_in[1];
    const float* k2 = (const float*)d_in[2];
    const float* a1 = (const float*)d_in[3];
    const float* a2 = (const float*)d_in[4];
    float* out = (float*)d_out;

    const int pts = GN * GN;                 // 262144
    const int blocks = pts / 256;            // 1024

    const float* src = u0;
    for (int s = 0; s < NSTEPS; ++s) {
        float* dst = out + (size_t)s * pts;
        heat_step<<<blocks, 256, 0, stream>>>(src, dst, k1, k2, a1, a2);
        src = dst;
    }
}

// Round 2
// 590.471 us; speedup vs baseline: 2.4098x; 2.4098x over previous
//
#include <hip/hip_runtime.h>

// Heat equation, 2 materials, N=512, 499 steps, all frames written.
// Temporal tiling: K=16 steps per launch. Each block owns a 32x32 tile,
// loads a 64x64 halo'd region, keeps per-thread 4x4 state in REGISTERS
// across steps, exchanges only the tile ring via double-buffered LDS.
// Validity trapezoid shrinks 1/step; owned region [16,48)^2 stays exact
// for steps <= 16. 32 dispatches total (31x16 + 1x3).

#define GN 512
#define NSTEPS 499
#define MBND 256
#define INV_DX2 261121.0f     // 511^2 = 1/dx^2
#define DT 5e-7f

#define TO 32                 // owned tile edge
#define KMAX 16               // halo width = max steps per launch
#define LOAD 64               // TO + 2*KMAX
#define LSTR 68               // padded LDS row stride (floats), %4==0 for b128

__global__ __launch_bounds__(256) void heat_multi(
    const float* __restrict__ Tin, float* __restrict__ outBase, int steps,
    const float* __restrict__ k1p, const float* __restrict__ k2p,
    const float* __restrict__ a1p, const float* __restrict__ a2p)
{
    __shared__ float buf[2][LOAD][LSTR];

    const int t  = threadIdx.x;
    const int bi = blockIdx.x >> 4;          // 16x16 tile grid
    const int bj = blockIdx.x & 15;
    const int gi0 = bi * TO - KMAX;          // top-left of loaded region
    const int gj0 = bj * TO - KMAX;

    // ---- stage initial 64x64 region into buf[0] (zero-fill out-of-grid)
    const bool inner = (gi0 >= 0) && (gi0 + LOAD <= GN) &&
                       (gj0 >= 0) && (gj0 + LOAD <= GN);
    if (inner) {
        #pragma unroll
        for (int k = 0; k < 4; ++k) {
            int g4 = t + 256 * k;
            int r = g4 >> 4, c4 = (g4 & 15) * 4;
            float4 v = *(const float4*)&Tin[(size_t)(gi0 + r) * GN + (gj0 + c4)];
            *(float4*)&buf[0][r][c4] = v;
        }
    } else {
        #pragma unroll
        for (int k = 0; k < 4; ++k) {
            int g4 = t + 256 * k;
            int r = g4 >> 4, c4 = (g4 & 15) * 4;
            int gi = gi0 + r;
            #pragma unroll
            for (int e = 0; e < 4; ++e) {
                int gj = gj0 + c4 + e;
                buf[0][r][c4 + e] = (gi >= 0 && gi < GN && gj >= 0 && gj < GN)
                                    ? Tin[(size_t)gi * GN + gj] : 0.0f;
            }
        }
    }
    __syncthreads();

    const int tx = t & 15, ty = t >> 4;
    const int li0 = ty * 4, lj0 = tx * 4;    // thread's 4x4 within 64x64
    // clamped halo row/col indices (edge threads read garbage -> outside
    // the validity trapezoid, never consumed by valid points)
    const int ra = (li0 == 0) ? 0 : li0 - 1;
    const int rb = (li0 == LOAD - 4) ? LOAD - 1 : li0 + 4;
    const int ca = (lj0 == 0) ? 0 : lj0 - 1;
    const int cb = (lj0 == LOAD - 4) ? LOAD - 1 : lj0 + 4;

    const float k1 = k1p[0], k2 = k2p[0];
    const float a1 = a1p[0], a2 = a2p[0];
    const float invk = 1.0f / (k1 + k2);

    float Acol[4]; bool ifc[4], bc[4], br[4];
    #pragma unroll
    for (int j = 0; j < 4; ++j) {
        int gj = gj0 + lj0 + j;
        Acol[j] = (DT * INV_DX2) * ((gj < MBND) ? a1 : a2);
        ifc[j] = (gj == MBND - 1);
        bc[j]  = (gj <= 0) || (gj >= GN - 1);   // boundary or out-of-grid
    }
    #pragma unroll
    for (int i = 0; i < 4; ++i) {
        int gi = gi0 + li0 + i;
        br[i] = (gi <= 0) || (gi >= GN - 1);
    }

    const bool owned = (tx >= 4) && (tx < 12) && (ty >= 4) && (ty < 12);

    // init register state from staged tile
    float R[4][4];
    #pragma unroll
    for (int i = 0; i < 4; ++i) {
        float4 v = *(const float4*)&buf[0][li0 + i][lj0];
        R[i][0] = v.x; R[i][1] = v.y; R[i][2] = v.z; R[i][3] = v.w;
    }

    for (int s = 1; s <= steps; ++s) {
        const float (*B)[LSTR] = buf[(s - 1) & 1];
        float top[4], bot[4], lf[4], rg[4];
        #pragma unroll
        for (int j = 0; j < 4; ++j) { top[j] = B[ra][lj0 + j]; bot[j] = B[rb][lj0 + j]; }
        #pragma unroll
        for (int i = 0; i < 4; ++i) { lf[i] = B[li0 + i][ca]; rg[i] = B[li0 + i][cb]; }

        float Nv[4][4];
        #pragma unroll
        for (int i = 0; i < 4; ++i) {
            #pragma unroll
            for (int j = 0; j < 4; ++j) {
                float up = (i == 0) ? top[j] : R[i - 1][j];
                float dn = (i == 3) ? bot[j] : R[i + 1][j];
                float le = (j == 0) ? lf[i]  : R[i][j - 1];
                float ri = (j == 3) ? rg[i]  : R[i][j + 1];
                float c  = R[i][j];
                float sum = (up + dn) + (le + ri);
                float v  = fmaf(Acol[j], fmaf(-4.0f, c, sum), c);
                float fv = (k1 * ri + k2 * le) * invk;   // interface from OLD T
                v = ifc[j] ? fv : v;
                v = (bc[j] || br[i]) ? 0.0f : v;
                Nv[i][j] = v;
            }
        }
        #pragma unroll
        for (int i = 0; i < 4; ++i)
            #pragma unroll
            for (int j = 0; j < 4; ++j) R[i][j] = Nv[i][j];

        // publish ring (only values neighbors read) to the other buffer
        float (*W)[LSTR] = buf[s & 1];
        *(float4*)&W[li0][lj0]     = make_float4(R[0][0], R[0][1], R[0][2], R[0][3]);
        *(float4*)&W[li0 + 3][lj0] = make_float4(R[3][0], R[3][1], R[3][2], R[3][3]);
        W[li0 + 1][lj0] = R[1][0]; W[li0 + 1][lj0 + 3] = R[1][3];
        W[li0 + 2][lj0] = R[2][0]; W[li0 + 2][lj0 + 3] = R[2][3];

        // stream this frame's owned tile straight from registers
        if (owned) {
            float* dst = outBase + (size_t)(s - 1) * (GN * GN)
                       + (size_t)(gi0 + li0) * GN + (gj0 + lj0);
            #pragma unroll
            for (int i = 0; i < 4; ++i)
                *(float4*)&dst[(size_t)i * GN] = make_float4(R[i][0], R[i][1], R[i][2], R[i][3]);
        }
        __syncthreads();
    }
}

extern "C" void kernel_launch(void* const* d_in, const int* in_sizes, int n_in,
                              void* d_out, int out_size, void* d_ws, size_t ws_size,
                              hipStream_t stream)
{
    const float* u0 = (const float*)d_in[0];
    const float* k1 = (const float*)d_in[1];
    const float* k2 = (const float*)d_in[2];
    const float* a1 = (const float*)d_in[3];
    const float* a2 = (const float*)d_in[4];
    float* out = (float*)d_out;

    const int pts = GN * GN;
    const float* src = u0;
    int done = 0;
    while (done < NSTEPS) {
        const int steps = (NSTEPS - done < KMAX) ? (NSTEPS - done) : KMAX;
        float* ob = out + (size_t)done * pts;
        heat_multi<<<256, 256, 0, stream>>>(src, ob, steps, k1, k2, a1, a2);
        src = ob + (size_t)(steps - 1) * pts;
        done += steps;
    }
}

// Round 3
// 498.431 us; speedup vs baseline: 2.8548x; 1.1847x over previous
//
#include <hip/hip_runtime.h>

// Heat equation, 2 materials, N=512, 499 steps, all frames written.
// Temporal tiling: K=16 steps/launch, 32 dispatches. Block = 512 threads,
// each owning a 2x4 register tile of a 64x64 halo'd region (owned 32x32).
// Per-step sync is an LDS-ONLY barrier (lgkmcnt + raw s_barrier) so global
// frame stores never drain on the step critical path.

#define GN 512
#define NSTEPS 499
#define MBND 256
#define INV_DX2 261121.0f     // 511^2 = 1/dx^2
#define DT 5e-7f

#define TO 32                 // owned tile edge
#define KMAX 16               // halo width = max steps per launch
#define LOAD 64               // TO + 2*KMAX
#define LSTR 68               // padded LDS row stride (floats)

__device__ __forceinline__ void lds_barrier() {
    // LDS-visibility-only workgroup barrier: do NOT drain vmcnt (global
    // frame stores stay in flight across steps).
    asm volatile("s_waitcnt lgkmcnt(0)" ::: "memory");
    __builtin_amdgcn_s_barrier();
    asm volatile("" ::: "memory");
}

__global__ __launch_bounds__(512) void heat_multi(
    const float* __restrict__ Tin, float* __restrict__ outBase, int steps,
    const float* __restrict__ k1p, const float* __restrict__ k2p,
    const float* __restrict__ a1p, const float* __restrict__ a2p)
{
    __shared__ float buf[2][LOAD][LSTR];

    const int t  = threadIdx.x;              // 0..511
    const int bi = blockIdx.x >> 4;          // 16x16 tile grid
    const int bj = blockIdx.x & 15;
    const int gi0 = bi * TO - KMAX;          // top-left of loaded region
    const int gj0 = bj * TO - KMAX;

    // ---- stage initial 64x64 region into buf[0] (zero-fill out-of-grid)
    const bool inner = (gi0 >= 0) && (gi0 + LOAD <= GN) &&
                       (gj0 >= 0) && (gj0 + LOAD <= GN);
    if (inner) {
        #pragma unroll
        for (int k = 0; k < 2; ++k) {
            int g4 = t + 512 * k;                 // over 1024 float4s
            int r = g4 >> 4, c4 = (g4 & 15) * 4;
            float4 v = *(const float4*)&Tin[(size_t)(gi0 + r) * GN + (gj0 + c4)];
            *(float4*)&buf[0][r][c4] = v;
        }
    } else {
        #pragma unroll
        for (int k = 0; k < 2; ++k) {
            int g4 = t + 512 * k;
            int r = g4 >> 4, c4 = (g4 & 15) * 4;
            int gi = gi0 + r;
            #pragma unroll
            for (int e = 0; e < 4; ++e) {
                int gj = gj0 + c4 + e;
                buf[0][r][c4 + e] = (gi >= 0 && gi < GN && gj >= 0 && gj < GN)
                                    ? Tin[(size_t)gi * GN + gj] : 0.0f;
            }
        }
    }
    lds_barrier();

    const int tx = t & 15, ty = t >> 4;      // 32 rows x 16 cols of threads
    const int li0 = ty * 2, lj0 = tx * 4;    // thread's 2x4 within 64x64
    // clamped halo indices (edge threads read garbage -> outside the
    // validity trapezoid, never consumed by valid points)
    const int ra = (li0 == 0) ? 0 : li0 - 1;
    const int rb = (li0 == LOAD - 2) ? LOAD - 1 : li0 + 2;
    const int ca = (lj0 == 0) ? 0 : lj0 - 1;
    const int cb = (lj0 == LOAD - 4) ? LOAD - 1 : lj0 + 4;

    const float k1 = k1p[0], k2 = k2p[0];
    const float a1 = a1p[0], a2 = a2p[0];
    const float invk = 1.0f / (k1 + k2);

    float Acol[4]; bool ifc[4], bc[4];
    #pragma unroll
    for (int j = 0; j < 4; ++j) {
        int gj = gj0 + lj0 + j;
        Acol[j] = (DT * INV_DX2) * ((gj < MBND) ? a1 : a2);
        ifc[j] = (gj == MBND - 1);
        bc[j]  = (gj <= 0) || (gj >= GN - 1);
    }
    bool br[2];
    #pragma unroll
    for (int i = 0; i < 2; ++i) {
        int gi = gi0 + li0 + i;
        br[i] = (gi <= 0) || (gi >= GN - 1);
    }

    const bool owned = (tx >= 4) && (tx < 12) && (ty >= 8) && (ty < 24);

    // init register state from staged tile
    float R[2][4];
    #pragma unroll
    for (int i = 0; i < 2; ++i) {
        float4 v = *(const float4*)&buf[0][li0 + i][lj0];
        R[i][0] = v.x; R[i][1] = v.y; R[i][2] = v.z; R[i][3] = v.w;
    }

    for (int s = 1; s <= steps; ++s) {
        const float (*B)[LSTR] = buf[(s - 1) & 1];
        float top[4], bot[4], lf[2], rg[2];
        #pragma unroll
        for (int j = 0; j < 4; ++j) { top[j] = B[ra][lj0 + j]; bot[j] = B[rb][lj0 + j]; }
        #pragma unroll
        for (int i = 0; i < 2; ++i) { lf[i] = B[li0 + i][ca]; rg[i] = B[li0 + i][cb]; }

        float Nv[2][4];
        #pragma unroll
        for (int i = 0; i < 2; ++i) {
            #pragma unroll
            for (int j = 0; j < 4; ++j) {
                float up = (i == 0) ? top[j] : R[0][j];
                float dn = (i == 1) ? bot[j] : R[1][j];
                float le = (j == 0) ? lf[i]  : R[i][j - 1];
                float ri = (j == 3) ? rg[i]  : R[i][j + 1];
                float c  = R[i][j];
                float sum = (up + dn) + (le + ri);
                float v  = fmaf(Acol[j], fmaf(-4.0f, c, sum), c);
                float fv = (k1 * ri + k2 * le) * invk;   // interface from OLD T
                v = ifc[j] ? fv : v;
                v = (bc[j] || br[i]) ? 0.0f : v;
                Nv[i][j] = v;
            }
        }
        #pragma unroll
        for (int i = 0; i < 2; ++i)
            #pragma unroll
            for (int j = 0; j < 4; ++j) R[i][j] = Nv[i][j];

        // publish full 2x4 tile (covers all halo needs of neighbors)
        float (*W)[LSTR] = buf[s & 1];
        *(float4*)&W[li0][lj0]     = make_float4(R[0][0], R[0][1], R[0][2], R[0][3]);
        *(float4*)&W[li0 + 1][lj0] = make_float4(R[1][0], R[1][1], R[1][2], R[1][3]);

        // stream this frame's owned tile straight from registers (async;
        // never drained by the per-step barrier)
        if (owned) {
            float* dst = outBase + (size_t)(s - 1) * (GN * GN)
                       + (size_t)(gi0 + li0) * GN + (gj0 + lj0);
            *(float4*)&dst[0]  = make_float4(R[0][0], R[0][1], R[0][2], R[0][3]);
            *(float4*)&dst[GN] = make_float4(R[1][0], R[1][1], R[1][2], R[1][3]);
        }
        lds_barrier();
    }
}

extern "C" void kernel_launch(void* const* d_in, const int* in_sizes, int n_in,
                              void* d_out, int out_size, void* d_ws, size_t ws_size,
                              hipStream_t stream)
{
    const float* u0 = (const float*)d_in[0];
    const float* k1 = (const float*)d_in[1];
    const float* k2 = (const float*)d_in[2];
    const float* a1 = (const float*)d_in[3];
    const float* a2 = (const float*)d_in[4];
    float* out = (float*)d_out;

    const int pts = GN * GN;
    const float* src = u0;
    int done = 0;
    while (done < NSTEPS) {
        const int steps = (NSTEPS - done < KMAX) ? (NSTEPS - done) : KMAX;
        float* ob = out + (size_t)done * pts;
        heat_multi<<<256, 512, 0, stream>>>(src, ob, steps, k1, k2, a1, a2);
        src = ob + (size_t)(steps - 1) * pts;
        done += steps;
    }
}

// Round 4
// 369.973 us; speedup vs baseline: 3.8460x; 1.3472x over previous
//
#include <hip/hip_runtime.h>

// Heat equation, 2 materials, N=512, 499 steps, all frames written.
// Temporal tiling: K=16 steps/launch, 32 dispatches. Block = 1024 threads
// (16 waves/CU = 4 waves/SIMD for latency hiding), each thread owns a 1x4
// register strip of a 64x64 halo'd region (owned 32x32 per block).
// Per-step sync is an LDS-ONLY barrier (lgkmcnt + raw s_barrier) so global
// frame stores never drain on the step critical path.

#define GN 512
#define NSTEPS 499
#define MBND 256
#define INV_DX2 261121.0f     // 511^2 = 1/dx^2
#define DT 5e-7f

#define TO 32                 // owned tile edge
#define KMAX 16               // halo width = max steps per launch
#define LOAD 64               // TO + 2*KMAX
#define LSTR 68               // padded LDS row stride (floats)

__device__ __forceinline__ void lds_barrier() {
    // LDS-visibility-only workgroup barrier: do NOT drain vmcnt (global
    // frame stores stay in flight across steps).
    asm volatile("s_waitcnt lgkmcnt(0)" ::: "memory");
    __builtin_amdgcn_s_barrier();
    asm volatile("" ::: "memory");
}

__global__ __launch_bounds__(1024) void heat_multi(
    const float* __restrict__ Tin, float* __restrict__ outBase, int steps,
    const float* __restrict__ k1p, const float* __restrict__ k2p,
    const float* __restrict__ a1p, const float* __restrict__ a2p)
{
    __shared__ float buf[2][LOAD][LSTR];

    const int t  = threadIdx.x;              // 0..1023
    const int bi = blockIdx.x >> 4;          // 16x16 tile grid
    const int bj = blockIdx.x & 15;
    const int gi0 = bi * TO - KMAX;          // top-left of loaded region
    const int gj0 = bj * TO - KMAX;

    // ---- stage initial 64x64 region into buf[0]: exactly 1 float4/thread
    {
        const int r  = t >> 4;               // 0..63
        const int c4 = (t & 15) * 4;         // 0..60
        const bool inner = (gi0 >= 0) && (gi0 + LOAD <= GN) &&
                           (gj0 >= 0) && (gj0 + LOAD <= GN);
        if (inner) {
            float4 v = *(const float4*)&Tin[(size_t)(gi0 + r) * GN + (gj0 + c4)];
            *(float4*)&buf[0][r][c4] = v;
        } else {
            int gi = gi0 + r;
            #pragma unroll
            for (int e = 0; e < 4; ++e) {
                int gj = gj0 + c4 + e;
                buf[0][r][c4 + e] = (gi >= 0 && gi < GN && gj >= 0 && gj < GN)
                                    ? Tin[(size_t)gi * GN + gj] : 0.0f;
            }
        }
    }
    lds_barrier();

    const int tx = t & 15, ty = t >> 4;      // 64 rows x 16 col-groups
    const int lj0 = tx * 4;                  // thread's 1x4 strip at row ty
    // clamped halo indices (edge threads read garbage -> outside the
    // validity trapezoid, never consumed by valid points)
    const int ra = (ty == 0) ? 0 : ty - 1;
    const int rb = (ty == LOAD - 1) ? LOAD - 1 : ty + 1;
    const int ca = (lj0 == 0) ? 0 : lj0 - 1;
    const int cb = (lj0 == LOAD - 4) ? LOAD - 1 : lj0 + 4;

    const float k1 = k1p[0], k2 = k2p[0];
    const float a1 = a1p[0], a2 = a2p[0];
    const float invk = 1.0f / (k1 + k2);

    float Acol[4]; bool ifc[4], bc[4];
    #pragma unroll
    for (int j = 0; j < 4; ++j) {
        int gj = gj0 + lj0 + j;
        Acol[j] = (DT * INV_DX2) * ((gj < MBND) ? a1 : a2);
        ifc[j] = (gj == MBND - 1);
        bc[j]  = (gj <= 0) || (gj >= GN - 1);
    }
    const int gi = gi0 + ty;
    const bool brow = (gi <= 0) || (gi >= GN - 1);

    const bool owned = (tx >= 4) && (tx < 12) && (ty >= KMAX) && (ty < KMAX + TO);
    float* dst = outBase + (size_t)gi * GN + (gj0 + lj0);

    // init register state from staged tile
    float R[4];
    {
        float4 v = *(const float4*)&buf[0][ty][lj0];
        R[0] = v.x; R[1] = v.y; R[2] = v.z; R[3] = v.w;
    }

    for (int s = 1; s <= steps; ++s) {
        const float (*B)[LSTR] = buf[(s - 1) & 1];
        const float4 top = *(const float4*)&B[ra][lj0];
        const float4 bot = *(const float4*)&B[rb][lj0];
        const float  lf  = B[ty][ca];
        const float  rg  = B[ty][cb];
        const float tops[4] = {top.x, top.y, top.z, top.w};
        const float bots[4] = {bot.x, bot.y, bot.z, bot.w};

        float Nv[4];
        #pragma unroll
        for (int j = 0; j < 4; ++j) {
            float le = (j == 0) ? lf : R[j - 1];
            float ri = (j == 3) ? rg : R[j + 1];
            float c  = R[j];
            float sum = (tops[j] + bots[j]) + (le + ri);
            float v  = fmaf(Acol[j], fmaf(-4.0f, c, sum), c);
            float fv = (k1 * ri + k2 * le) * invk;   // interface from OLD T
            v = ifc[j] ? fv : v;
            v = (bc[j] || brow) ? 0.0f : v;
            Nv[j] = v;
        }
        #pragma unroll
        for (int j = 0; j < 4; ++j) R[j] = Nv[j];

        // publish full 1x4 strip (covers all halo needs of neighbors)
        float (*W)[LSTR] = buf[s & 1];
        *(float4*)&W[ty][lj0] = make_float4(R[0], R[1], R[2], R[3]);

        // stream this frame's owned strip straight from registers (async;
        // never drained by the per-step barrier)
        if (owned) {
            *(float4*)dst = make_float4(R[0], R[1], R[2], R[3]);
        }
        dst += (size_t)GN * GN;
        lds_barrier();
    }
}

extern "C" void kernel_launch(void* const* d_in, const int* in_sizes, int n_in,
                              void* d_out, int out_size, void* d_ws, size_t ws_size,
                              hipStream_t stream)
{
    const float* u0 = (const float*)d_in[0];
    const float* k1 = (const float*)d_in[1];
    const float* k2 = (const float*)d_in[2];
    const float* a1 = (const float*)d_in[3];
    const float* a2 = (const float*)d_in[4];
    float* out = (float*)d_out;

    const int pts = GN * GN;
    const float* src = u0;
    int done = 0;
    while (done < NSTEPS) {
        const int steps = (NSTEPS - done < KMAX) ? (NSTEPS - done) : KMAX;
        float* ob = out + (size_t)done * pts;
        heat_multi<<<256, 1024, 0, stream>>>(src, ob, steps, k1, k2, a1, a2);
        src = ob + (size_t)(steps - 1) * pts;
        done += steps;
    }
}

// Round 5
// 362.785 us; speedup vs baseline: 3.9222x; 1.0198x over previous
//
#include <hip/hip_runtime.h>

// Heat equation, 2 materials, N=512, 499 steps, all frames written.
// Temporal tiling: K=16 steps/launch, 32 dispatches, 1024-thread blocks,
// thread owns a 1x4 strip of a 64x64 halo'd region (owned 32x32/block).
// R5: left/right via wave shuffles (lane±1), STEPS templated + fully
// unrolled, interface/boundary fixups behind block-uniform branches,
// LDS-only per-step barrier (no vmcnt drain), no final barrier.

#define GN 512
#define NSTEPS 499
#define MBND 256
#define INV_DX2 261121.0f     // 511^2 = 1/dx^2
#define DT 5e-7f

#define TO 32                 // owned tile edge
#define KMAX 16               // halo width = max steps per launch
#define LOAD 64               // TO + 2*KMAX
#define LSTR 68               // padded LDS row stride (floats)

__device__ __forceinline__ void lds_barrier() {
    // LDS-visibility-only workgroup barrier: do NOT drain vmcnt (global
    // frame stores stay in flight across steps).
    asm volatile("s_waitcnt lgkmcnt(0)" ::: "memory");
    __builtin_amdgcn_s_barrier();
    asm volatile("" ::: "memory");
}

template<int STEPS>
__global__ __launch_bounds__(1024) void heat_multi(
    const float* __restrict__ Tin, float* __restrict__ outBase,
    const float* __restrict__ k1p, const float* __restrict__ k2p,
    const float* __restrict__ a1p, const float* __restrict__ a2p)
{
    __shared__ float buf[2][LOAD][LSTR];

    const int t  = threadIdx.x;              // 0..1023
    const int bi = blockIdx.x >> 4;          // 16x16 tile grid
    const int bj = blockIdx.x & 15;
    const int gi0 = bi * TO - KMAX;          // top-left of loaded region
    const int gj0 = bj * TO - KMAX;

    // ---- stage initial 64x64 region into buf[0]: exactly 1 float4/thread
    {
        const int r  = t >> 4;               // 0..63
        const int c4 = (t & 15) * 4;         // 0..60
        const bool innerB = (gi0 >= 0) && (gi0 + LOAD <= GN) &&
                            (gj0 >= 0) && (gj0 + LOAD <= GN);
        if (innerB) {
            float4 v = *(const float4*)&Tin[(size_t)(gi0 + r) * GN + (gj0 + c4)];
            *(float4*)&buf[0][r][c4] = v;
        } else {
            const int gi = gi0 + r;
            #pragma unroll
            for (int e = 0; e < 4; ++e) {
                const int gj = gj0 + c4 + e;
                buf[0][r][c4 + e] = (gi >= 0 && gi < GN && gj >= 0 && gj < GN)
                                    ? Tin[(size_t)gi * GN + gj] : 0.0f;
            }
        }
    }

    const int tx = t & 15, ty = t >> 4;      // 64 rows x 16 col-groups
    const int lj0 = tx * 4;                  // thread's 1x4 strip at row ty
    const int ra = (ty == 0) ? 0 : ty - 1;   // clamped halo rows (junk-safe:
    const int rb = (ty == LOAD - 1) ? LOAD - 1 : ty + 1;  // outside trapezoid)

    const float k1 = k1p[0], k2 = k2p[0];
    const float a1 = a1p[0], a2 = a2p[0];
    const float invk = 1.0f / (k1 + k2);

    float Acol[4]; bool ifc[4], bc[4];
    #pragma unroll
    for (int j = 0; j < 4; ++j) {
        const int gj = gj0 + lj0 + j;
        Acol[j] = (DT * INV_DX2) * ((gj < MBND) ? a1 : a2);
        ifc[j] = (gj == MBND - 1);
        bc[j]  = (gj <= 0) || (gj >= GN - 1);
    }
    const int gi = gi0 + ty;
    const bool brow = (gi <= 0) || (gi >= GN - 1);

    // block-uniform specialization flags (scalar branches)
    const bool anyIfc = (gj0 <= MBND - 1) && (MBND - 1 < gj0 + LOAD); // bj 7,8
    const bool anyBC  = (gj0 <= 0) || (gj0 + LOAD >= GN);             // bj 0,15
    const bool anyBR  = (gi0 <= 0) || (gi0 + LOAD >= GN);             // bi 0,15

    const bool owned = (tx >= 4) && (tx < 12) && (ty >= KMAX) && (ty < KMAX + TO);
    float* dst = outBase + ((size_t)gi * GN + (gj0 + lj0));

    lds_barrier();
    float R[4];
    {
        const float4 v = *(const float4*)&buf[0][ty][lj0];
        R[0] = v.x; R[1] = v.y; R[2] = v.z; R[3] = v.w;
    }

    #pragma unroll
    for (int s = 1; s <= STEPS; ++s) {
        // left/right neighbor floats via wave shuffle of PRE-update R.
        // Within-row neighbors are lane±1 (16 lanes per row). Edge lanes
        // (tx==0 / tx==15) get junk -> feeds only trapezoid-invalid cols.
        const float lf = __shfl_up(R[3], 1);
        const float rg = __shfl_down(R[0], 1);

        const float (*B)[LSTR] = buf[(s - 1) & 1];    // compile-time parity
        const float4 top = *(const float4*)&B[ra][lj0];
        const float4 bot = *(const float4*)&B[rb][lj0];

        const float le0 = lf,   le1 = R[0], le2 = R[1], le3 = R[2];
        const float ri0 = R[1], ri1 = R[2], ri2 = R[3], ri3 = rg;

        float Nv[4];
        Nv[0] = fmaf(Acol[0], fmaf(-4.0f, R[0], (top.x + bot.x) + (le0 + ri0)), R[0]);
        Nv[1] = fmaf(Acol[1], fmaf(-4.0f, R[1], (top.y + bot.y) + (le1 + ri1)), R[1]);
        Nv[2] = fmaf(Acol[2], fmaf(-4.0f, R[2], (top.z + bot.z) + (le2 + ri2)), R[2]);
        Nv[3] = fmaf(Acol[3], fmaf(-4.0f, R[3], (top.w + bot.w) + (le3 + ri3)), R[3]);

        if (anyIfc) {   // interface column from OLD T neighbors
            const float le[4] = {le0, le1, le2, le3};
            const float ri[4] = {ri0, ri1, ri2, ri3};
            #pragma unroll
            for (int j = 0; j < 4; ++j)
                Nv[j] = ifc[j] ? (k1 * ri[j] + k2 * le[j]) * invk : Nv[j];
        }
        if (anyBC) {    // Dirichlet zero: boundary columns
            #pragma unroll
            for (int j = 0; j < 4; ++j) Nv[j] = bc[j] ? 0.0f : Nv[j];
        }
        if (anyBR) {    // Dirichlet zero: boundary rows (after interface)
            #pragma unroll
            for (int j = 0; j < 4; ++j) Nv[j] = brow ? 0.0f : Nv[j];
        }
        R[0] = Nv[0]; R[1] = Nv[1]; R[2] = Nv[2]; R[3] = Nv[3];

        // publish full 1x4 strip (covers neighbors' top/bot reads)
        float (*W)[LSTR] = buf[s & 1];
        *(float4*)&W[ty][lj0] = make_float4(R[0], R[1], R[2], R[3]);

        // stream this frame's owned strip (async; never drained per-step)
        if (owned) *(float4*)dst = make_float4(R[0], R[1], R[2], R[3]);
        dst += (size_t)GN * GN;

        if (s < STEPS) lds_barrier();      // last step: no barrier needed
    }
}

extern "C" void kernel_launch(void* const* d_in, const int* in_sizes, int n_in,
                              void* d_out, int out_size, void* d_ws, size_t ws_size,
                              hipStream_t stream)
{
    const float* u0 = (const float*)d_in[0];
    const float* k1 = (const float*)d_in[1];
    const float* k2 = (const float*)d_in[2];
    const float* a1 = (const float*)d_in[3];
    const float* a2 = (const float*)d_in[4];
    float* out = (float*)d_out;

    const int pts = GN * GN;
    const float* src = u0;
    int done = 0;
    while (done < NSTEPS) {
        int steps = NSTEPS - done;
        if (steps > KMAX) steps = KMAX;
        float* ob = out + (size_t)done * pts;
        if (steps == KMAX)
            heat_multi<KMAX><<<256, 1024, 0, stream>>>(src, ob, k1, k2, a1, a2);
        else  // NSTEPS = 31*16 + 3 -> remainder is always 3
            heat_multi<3><<<256, 1024, 0, stream>>>(src, ob, k1, k2, a1, a2);
        src = ob + (size_t)(steps - 1) * pts;
        done += steps;
    }
}